// Round 6
// baseline (61.048 us; speedup 1.0000x reference)
//
#include <hip/hip_runtime.h>
#include <math.h>

#define EPS 1e-4f
#define N_   32
#define CIN  128
#define L_   512
#define CP   64
#define P_   2000
#define NCLS 200

typedef __attribute__((ext_vector_type(8))) short bf16x8;
typedef __attribute__((ext_vector_type(4))) float f32x4;

__device__ inline unsigned short f2bf_rne(float f) {
    unsigned int u = __float_as_uint(f);
    unsigned int r = u + 0x7FFFu + ((u >> 16) & 1u);
    return (unsigned short)(r >> 16);
}
__device__ inline float bf2f(unsigned short h) {
    return __uint_as_float(((unsigned int)h) << 16);
}

// ---------------- Kernel 1: conv1x1 -> relu -> conv1x1 -> sigmoid ----------------
// 256 blocks x 512 threads. Wave wv owns 8 output channels (wave-uniform -> W via
// s_load, scalar FMA operand); lane owns one l (x column in VGPRs, no LDS for
// phase 1). Only LDS: h exchange [c][l], store bounce, x2 partials.
__global__ __launch_bounds__(512) void k1_conv(const float* __restrict__ x,
    const float* __restrict__ W1, const float* __restrict__ b1,
    const float* __restrict__ W2, const float* __restrict__ b2,
    unsigned short* __restrict__ fTh, unsigned short* __restrict__ fTl,
    float* __restrict__ x2buf)
{
    __shared__ float hS[64*64];      // [c][l] 16KB
    __shared__ uint4 fP[2][64][8];   // [buf][l][c-group] swizzled bounce 16KB
    __shared__ float x2p[8][64];     // 2KB

    const int tid  = threadIdx.x;
    const int lane = tid & 63;
    const int wv   = tid >> 6;          // 0..7
    const int n    = blockIdx.y;
    const int lg   = blockIdx.x;        // 0..7, 64 l each

    const int orow = __builtin_amdgcn_readfirstlane(wv * 8);

    // ---- x column for this lane, in registers (128 coalesced dword loads) ----
    float xr[128];
    const float* xg = x + (size_t)n*CIN*L_ + lg*64 + lane;
    #pragma unroll
    for (int c = 0; c < 128; ++c) xr[c] = xg[(size_t)c*L_];

    // ---- phase 1: h = relu(W1 @ x + b1), W via scalar loads ----
    const float4* W1u = (const float4*)(W1 + (size_t)orow*CIN);
    float h[8];
    #pragma unroll
    for (int o = 0; o < 8; ++o) h[o] = b1[orow + o];
    #pragma unroll
    for (int c4 = 0; c4 < 32; ++c4) {
        #pragma unroll
        for (int o = 0; o < 8; ++o) {
            float4 w = W1u[o*32 + c4];
            h[o] = fmaf(w.x, xr[c4*4+0], fmaf(w.y, xr[c4*4+1],
                   fmaf(w.z, xr[c4*4+2], fmaf(w.w, xr[c4*4+3], h[o]))));
        }
    }
    #pragma unroll
    for (int o = 0; o < 8; ++o) hS[(orow+o)*64 + lane] = fmaxf(h[o], 0.f);
    __syncthreads();

    // ---- phase 2: f = sigmoid(W2 @ h + b2) ----
    const float4* W2u = (const float4*)(W2 + (size_t)orow*CP);
    float f[8];
    #pragma unroll
    for (int o = 0; o < 8; ++o) f[o] = b2[orow + o];
    #pragma unroll 4
    for (int c4 = 0; c4 < 16; ++c4) {
        float h0 = hS[(c4*4+0)*64 + lane];
        float h1 = hS[(c4*4+1)*64 + lane];
        float h2 = hS[(c4*4+2)*64 + lane];
        float h3 = hS[(c4*4+3)*64 + lane];
        #pragma unroll
        for (int o = 0; o < 8; ++o) {
            float4 w = W2u[o*16 + c4];
            f[o] = fmaf(w.x, h0, fmaf(w.y, h1, fmaf(w.z, h2, fmaf(w.w, h3, f[o]))));
        }
    }

    // ---- sigmoid, split-bf16 pack, x2 partial ----
    unsigned int pH[4], pL[4];
    float s = 0.f;
    #pragma unroll
    for (int o = 0; o < 8; ++o) {
        float v = 1.f/(1.f + expf(-f[o]));
        unsigned short hb = f2bf_rne(v);
        unsigned short lb = f2bf_rne(v - bf2f(hb));
        if (o & 1) { pH[o>>1] |= (unsigned)hb << 16; pL[o>>1] |= (unsigned)lb << 16; }
        else       { pH[o>>1] = hb; pL[o>>1] = lb; }
        s = fmaf(v, v, s);
    }
    x2p[wv][lane] = s;
    fP[0][lane][wv ^ (lane & 7)] = make_uint4(pH[0],pH[1],pH[2],pH[3]);
    fP[1][lane][wv ^ (lane & 7)] = make_uint4(pL[0],pL[1],pL[2],pL[3]);
    __syncthreads();

    // ---- coalesced stores: [n][l][c] bf16, 8 uint4 per l ----
    uint4* gH4 = (uint4*)fTh + ((size_t)(n*L_ + lg*64))*8;
    uint4* gL4 = (uint4*)fTl + ((size_t)(n*L_ + lg*64))*8;
    {
        int row = tid >> 3, u = tid & 7;
        gH4[tid] = fP[0][row][u ^ (row & 7)];
        gL4[tid] = fP[1][row][u ^ (row & 7)];
    }
    if (tid < 64) {
        float v = 0.f;
        #pragma unroll
        for (int g = 0; g < 8; ++g) v += x2p[g][tid];
        x2buf[n*L_ + lg*64 + tid] = v;
    }
}

// ---------------- Kernel 2: split-bf16 MFMA distance scan + min + activation ----------------
__global__ __launch_bounds__(256, 2) void k2_dist(
    const unsigned short* __restrict__ fTh, const unsigned short* __restrict__ fTl,
    const float* __restrict__ x2buf, const float* __restrict__ proto,
    float* __restrict__ md_out, float* __restrict__ acts)
{
    __shared__ unsigned short fBh[8192];  // [128 l][64 k] bf16, XOR-swizzled rows (16KB)
    __shared__ unsigned short fBl[8192];
    __shared__ float x2S[128];
    __shared__ float redS[4][128];

    const int tid  = threadIdx.x;
    const int lane = tid & 63;
    const int wv   = tid >> 6;
    const int n    = blockIdx.y;
    const int p0   = blockIdx.x * 128;

    // ---- A fragments: proto f32 -> split bf16, kept in registers ----
    bf16x8 ah[8][2], al[8][2];
    {
        const int pr = lane & 15;
        const int g  = lane >> 4;
        #pragma unroll
        for (int ps = 0; ps < 8; ++ps) {
            int p = p0 + ps*16 + pr;
            #pragma unroll
            for (int ks = 0; ks < 2; ++ks) {
                float v[8];
                if (p < P_) {
                    const float4* src = (const float4*)(proto + (size_t)p*64 + ks*32 + g*8);
                    float4 a0 = src[0], a1 = src[1];
                    v[0]=a0.x; v[1]=a0.y; v[2]=a0.z; v[3]=a0.w;
                    v[4]=a1.x; v[5]=a1.y; v[6]=a1.z; v[7]=a1.w;
                } else {
                    #pragma unroll
                    for (int j = 0; j < 8; ++j) v[j] = 0.f;
                }
                bf16x8 H, Lo;
                #pragma unroll
                for (int j = 0; j < 8; ++j) {
                    unsigned short hb = f2bf_rne(v[j]);
                    unsigned short lb = f2bf_rne(v[j] - bf2f(hb));
                    H[j] = (short)hb; Lo[j] = (short)lb;
                }
                ah[ps][ks] = H; al[ps][ks] = Lo;
            }
        }
    }

    float rmin[8][4];
    #pragma unroll
    for (int ps = 0; ps < 8; ++ps)
        #pragma unroll
        for (int r = 0; r < 4; ++r) rmin[ps][r] = 3.0e38f;

    const char* gH = (const char*)(fTh + (size_t)n*L_*CP);
    const char* gL = (const char*)(fTl + (size_t)n*L_*CP);

    for (int ch = 0; ch < 4; ++ch) {
        __syncthreads();
        // stage 16KB per buffer: LDS[l*128 + (b ^ ((l&7)<<4))] = global[l*128 + b]
        #pragma unroll
        for (int s4 = 0; s4 < 4; ++s4) {
            int d  = (s4*256 + tid) * 16;
            int lr = d >> 7;
            int bo = d & 127;
            int ph = (lr << 7) + (bo ^ ((lr & 7) << 4));
            uint4 vh = *(const uint4*)(gH + (size_t)ch*16384 + d);
            uint4 vl = *(const uint4*)(gL + (size_t)ch*16384 + d);
            *(uint4*)((char*)fBh + ph) = vh;
            *(uint4*)((char*)fBl + ph) = vl;
        }
        if (tid < 128) x2S[tid] = x2buf[n*L_ + ch*128 + tid];
        __syncthreads();

        #pragma unroll
        for (int ls = 0; ls < 2; ++ls) {
            const int lsub = wv*2 + ls;
            const int lrow = lsub*16 + (lane & 15);
            const int g    = lane >> 4;
            bf16x8 bh[2], bl[2];
            #pragma unroll
            for (int ks = 0; ks < 2; ++ks) {
                int bo = (ks*64 + g*16) ^ ((lrow & 7) << 4);
                bh[ks] = *(const bf16x8*)((const char*)fBh + lrow*128 + bo);
                bl[ks] = *(const bf16x8*)((const char*)fBl + lrow*128 + bo);
            }
            float xv = x2S[lsub*16 + (lane & 15)];
            #pragma unroll
            for (int ps = 0; ps < 8; ++ps) {
                f32x4 c = {0.f, 0.f, 0.f, 0.f};
                c = __builtin_amdgcn_mfma_f32_16x16x32_bf16(ah[ps][0], bh[0], c, 0, 0, 0);
                c = __builtin_amdgcn_mfma_f32_16x16x32_bf16(ah[ps][1], bh[1], c, 0, 0, 0);
                c = __builtin_amdgcn_mfma_f32_16x16x32_bf16(al[ps][0], bh[0], c, 0, 0, 0);
                c = __builtin_amdgcn_mfma_f32_16x16x32_bf16(al[ps][1], bh[1], c, 0, 0, 0);
                c = __builtin_amdgcn_mfma_f32_16x16x32_bf16(ah[ps][0], bl[0], c, 0, 0, 0);
                c = __builtin_amdgcn_mfma_f32_16x16x32_bf16(ah[ps][1], bl[1], c, 0, 0, 0);
                #pragma unroll
                for (int r = 0; r < 4; ++r)
                    rmin[ps][r] = fminf(rmin[ps][r], fmaf(-2.f, c[r], xv));
            }
        }
    }

    // min over the 16 l-columns within each 16-lane group
    #pragma unroll
    for (int ps = 0; ps < 8; ++ps)
        #pragma unroll
        for (int r = 0; r < 4; ++r) {
            float v = rmin[ps][r];
            v = fminf(v, __shfl_xor(v, 1));
            v = fminf(v, __shfl_xor(v, 2));
            v = fminf(v, __shfl_xor(v, 4));
            v = fminf(v, __shfl_xor(v, 8));
            rmin[ps][r] = v;
        }
    if ((lane & 15) == 0) {
        const int g = lane >> 4;
        #pragma unroll
        for (int ps = 0; ps < 8; ++ps)
            #pragma unroll
            for (int r = 0; r < 4; ++r)
                redS[wv][ps*16 + g*4 + r] = rmin[ps][r];
    }
    __syncthreads();
    if (tid < 128) {
        float mv = fminf(fminf(redS[0][tid], redS[1][tid]), fminf(redS[2][tid], redS[3][tid]));
        int gp = p0 + tid;
        if (gp < P_) {
            const float4* pr = (const float4*)(proto + (size_t)gp*64);
            float p2 = 0.f;
            #pragma unroll
            for (int q = 0; q < 16; ++q) {
                float4 v = pr[q];
                p2 += v.x*v.x + v.y*v.y + v.z*v.z + v.w*v.w;
            }
            float m = fmaxf(mv + p2, 0.0f);
            md_out[n*P_ + gp] = m;
            acts[n*P_ + gp]   = logf((m + 1.0f) / (m + EPS));
        }
    }
}

// ---------------- Kernel 3: logits = acts @ last_w^T, one wave per output ----------------
__global__ __launch_bounds__(256) void k3_logits(const float* __restrict__ acts,
    const float* __restrict__ last_w, float* __restrict__ out)
{
    const int wid  = (blockIdx.x * 256 + threadIdx.x) >> 6;  // 0..6399
    const int lane = threadIdx.x & 63;
    const int n    = wid / NCLS;
    const int cls  = wid - n * NCLS;

    const float4* a = (const float4*)(acts + (size_t)n*P_);
    const float4* w = (const float4*)(last_w + (size_t)cls*P_);

    float acc = 0.f;
    #pragma unroll
    for (int it = 0; it < 8; ++it) {
        int idx = it*64 + lane;          // float4 index, 0..511
        if (idx < P_/4) {
            float4 av = a[idx]; float4 wv = w[idx];
            acc += av.x*wv.x + av.y*wv.y + av.z*wv.z + av.w*wv.w;
        }
    }
    #pragma unroll
    for (int off = 32; off > 0; off >>= 1)
        acc += __shfl_down(acc, off);
    if (lane == 0)
        out[n*NCLS + cls] = acc;
}

extern "C" void kernel_launch(void* const* d_in, const int* in_sizes, int n_in,
                              void* d_out, int out_size, void* d_ws, size_t ws_size,
                              hipStream_t stream)
{
    const float* x      = (const float*)d_in[0];
    const float* W1     = (const float*)d_in[1];
    const float* b1     = (const float*)d_in[2];
    const float* W2     = (const float*)d_in[3];
    const float* b2     = (const float*)d_in[4];
    const float* proto  = (const float*)d_in[5];
    const float* last_w = (const float*)d_in[6];

    float* out = (float*)d_out;   // [32*200] logits, then [32*2000] min_dist

    // ws layout: fTh 2MB | fTl 2MB | x2buf 64KB | acts 256KB
    unsigned short* fTh = (unsigned short*)d_ws;
    unsigned short* fTl = fTh + (size_t)N_*L_*CP;
    float* x2buf = (float*)(fTl + (size_t)N_*L_*CP);
    float* acts  = x2buf + (size_t)N_*L_;

    k1_conv  <<<dim3(8, 32),  512, 0, stream>>>(x, W1, b1, W2, b2, fTh, fTl, x2buf);
    k2_dist  <<<dim3(16, 32), 256, 0, stream>>>(fTh, fTl, x2buf, proto, out + N_*NCLS, acts);
    k3_logits<<<1600,         256, 0, stream>>>(acts, last_w, out);
}

// Round 7
// 60.346 us; speedup vs baseline: 1.0116x; 1.0116x over previous
//
#include <hip/hip_runtime.h>
#include <math.h>

#define EPS 1e-4f
#define N_   32
#define CIN  128
#define L_   512
#define CP   64
#define P_   2000
#define NCLS 200

typedef __attribute__((ext_vector_type(8))) short bf16x8;
typedef __attribute__((ext_vector_type(4))) float f32x4;

__device__ inline unsigned short f2bf_rne(float f) {
    unsigned int u = __float_as_uint(f);
    unsigned int r = u + 0x7FFFu + ((u >> 16) & 1u);
    return (unsigned short)(r >> 16);
}
__device__ inline float bf2f(unsigned short h) {
    return __uint_as_float(((unsigned int)h) << 16);
}

__device__ inline void gl_lds16(const void* g, void* l) {
    __builtin_amdgcn_global_load_lds(
        (const __attribute__((address_space(1))) unsigned int*)g,
        (__attribute__((address_space(3))) unsigned int*)l, 16, 0, 0);
}

// ---------------- Kernel 1 (R5 version — measured ~4-5us): conv-relu-conv-sigmoid ----------
// 512 blocks (2/CU): block = (n, 32 l). thread = (og: 8-ch group, l).
__global__ __launch_bounds__(256) void k1_conv(const float* __restrict__ x,
    const float* __restrict__ W1, const float* __restrict__ b1,
    const float* __restrict__ W2, const float* __restrict__ b2,
    unsigned short* __restrict__ fTh, unsigned short* __restrict__ fTl,
    float* __restrict__ x2buf)
{
    __shared__ float  xS[128*32];              // 16KB [c][l]
    __shared__ float4 W1s[64][32];             // 32KB [o][c4]
    __shared__ float4 W2s[64][16];             // 16KB [o][c4]
    __shared__ __align__(16) char scratch[8448];  // hS [64][33] f32  OR  fP [2][32][8] uint4
    __shared__ float  x2p[8][32];
    __shared__ float  b1s[64], b2s[64];

    float (*hS)[33]       = (float (*)[33])scratch;
    uint4 (*fP)[32][8]    = (uint4 (*)[32][8])scratch;

    const int tid = threadIdx.x;
    const int wv  = tid >> 6;
    const int n   = blockIdx.y;
    const int lg  = blockIdx.x;

    // ---- async stage x tile [128 c][32 l] into LDS ----
    {
        const float* xbase = x + (size_t)n*CIN*L_ + lg*32;
        const int lane = tid & 63;
        #pragma unroll
        for (int i = 0; i < 4; ++i) {
            int blk = wv*4 + i;                 // 1KB chunk = 8 c-rows
            const float* src = xbase + (size_t)(blk*8 + (lane >> 3))*L_ + (lane & 7)*4;
            gl_lds16(src, &xS[blk*256]);
        }
    }

    const float4* W1g = (const float4*)W1;
    #pragma unroll
    for (int i = 0; i < 8; ++i) {
        int idx = tid + i*256;
        W1s[idx >> 5][idx & 31] = W1g[idx];
    }
    const float4* W2g = (const float4*)W2;
    #pragma unroll
    for (int i = 0; i < 4; ++i) {
        int idx = tid + i*256;
        W2s[idx >> 4][idx & 15] = W2g[idx];
    }
    if (tid < 64) { b1s[tid] = b1[tid]; b2s[tid] = b2[tid]; }
    __syncthreads();

    const int l  = tid & 31;
    const int og = tid >> 5;        // 0..7, 8 output channels each

    float h[8];
    #pragma unroll
    for (int o = 0; o < 8; ++o) h[o] = b1s[og*8 + o];

    #pragma unroll 8
    for (int c4 = 0; c4 < 32; ++c4) {
        float xv0 = xS[(c4*4+0)*32 + l];
        float xv1 = xS[(c4*4+1)*32 + l];
        float xv2 = xS[(c4*4+2)*32 + l];
        float xv3 = xS[(c4*4+3)*32 + l];
        #pragma unroll
        for (int o = 0; o < 8; ++o) {
            float4 w = W1s[og*8+o][c4];
            h[o] = fmaf(w.x, xv0, fmaf(w.y, xv1, fmaf(w.z, xv2, fmaf(w.w, xv3, h[o]))));
        }
    }
    __syncthreads();   // xS done; scratch free to use as hS
    #pragma unroll
    for (int o = 0; o < 8; ++o)
        hS[og*8+o][l] = fmaxf(h[o], 0.0f);
    __syncthreads();

    float f[8];
    #pragma unroll
    for (int o = 0; o < 8; ++o) f[o] = b2s[og*8 + o];
    #pragma unroll 4
    for (int c4 = 0; c4 < 16; ++c4) {
        float h0 = hS[c4*4+0][l];
        float h1 = hS[c4*4+1][l];
        float h2 = hS[c4*4+2][l];
        float h3 = hS[c4*4+3][l];
        #pragma unroll
        for (int o = 0; o < 8; ++o) {
            float4 w = W2s[og*8+o][c4];
            f[o] = fmaf(w.x, h0, fmaf(w.y, h1, fmaf(w.z, h2, fmaf(w.w, h3, f[o]))));
        }
    }

    unsigned int packH[4], packL[4];
    float s = 0.0f;
    #pragma unroll
    for (int o = 0; o < 8; ++o) {
        float v = 1.0f / (1.0f + expf(-f[o]));
        unsigned short hb = f2bf_rne(v);
        unsigned short lb = f2bf_rne(v - bf2f(hb));
        if (o & 1) { packH[o>>1] |= ((unsigned)hb) << 16; packL[o>>1] |= ((unsigned)lb) << 16; }
        else       { packH[o>>1] = hb;                     packL[o>>1] = lb; }
        s = fmaf(v, v, s);
    }
    x2p[og][l] = s;
    __syncthreads();   // hS reads done; scratch reused as fP bounce

    fP[0][l][og ^ (l & 7)] = make_uint4(packH[0],packH[1],packH[2],packH[3]);
    fP[1][l][og ^ (l & 7)] = make_uint4(packL[0],packL[1],packL[2],packL[3]);
    __syncthreads();

    // coalesced stores: [n][l][c] bf16, 64 c per l = 8 uint4
    uint4* gH4 = (uint4*)fTh + ((size_t)(n*L_ + lg*32))*8;
    uint4* gL4 = (uint4*)fTl + ((size_t)(n*L_ + lg*32))*8;
    {
        int ll = tid >> 3, u = tid & 7;
        gH4[tid] = fP[0][ll][u ^ (ll & 7)];
        gL4[tid] = fP[1][ll][u ^ (ll & 7)];
    }
    if (tid < 32) {
        float v = 0.f;
        #pragma unroll
        for (int g = 0; g < 8; ++g) v += x2p[g][tid];
        x2buf[n*L_ + lg*32 + tid] = v;
    }
}

// ---------------- Kernel 2: split-bf16 MFMA distance scan + min + activation ----------------
// 64-proto tile per block (A-frags = 64 VGPR, no spill), grid 32x32 = 4 blocks/CU.
__global__ __launch_bounds__(256, 4) void k2_dist(
    const unsigned short* __restrict__ fTh, const unsigned short* __restrict__ fTl,
    const float* __restrict__ x2buf, const float* __restrict__ proto,
    float* __restrict__ md_out, float* __restrict__ acts)
{
    __shared__ unsigned short fBh[8192];  // [128 l][64 k] bf16, XOR-swizzled rows (16KB)
    __shared__ unsigned short fBl[8192];
    __shared__ float x2S[128];
    __shared__ float redS[4][64];

    const int tid  = threadIdx.x;
    const int lane = tid & 63;
    const int wv   = tid >> 6;
    const int n    = blockIdx.y;
    const int p0   = blockIdx.x * 64;

    // ---- A fragments: proto f32 -> split bf16, kept in registers (64 VGPRs) ----
    bf16x8 ah[4][2], al[4][2];
    {
        const int pr = lane & 15;
        const int g  = lane >> 4;
        #pragma unroll
        for (int ps = 0; ps < 4; ++ps) {
            int p = p0 + ps*16 + pr;
            #pragma unroll
            for (int ks = 0; ks < 2; ++ks) {
                float v[8];
                if (p < P_) {
                    const float4* src = (const float4*)(proto + (size_t)p*64 + ks*32 + g*8);
                    float4 a0 = src[0], a1 = src[1];
                    v[0]=a0.x; v[1]=a0.y; v[2]=a0.z; v[3]=a0.w;
                    v[4]=a1.x; v[5]=a1.y; v[6]=a1.z; v[7]=a1.w;
                } else {
                    #pragma unroll
                    for (int j = 0; j < 8; ++j) v[j] = 0.f;
                }
                bf16x8 H, Lo;
                #pragma unroll
                for (int j = 0; j < 8; ++j) {
                    unsigned short hb = f2bf_rne(v[j]);
                    unsigned short lb = f2bf_rne(v[j] - bf2f(hb));
                    H[j] = (short)hb; Lo[j] = (short)lb;
                }
                ah[ps][ks] = H; al[ps][ks] = Lo;
            }
        }
    }

    float rmin[4][4];
    #pragma unroll
    for (int ps = 0; ps < 4; ++ps)
        #pragma unroll
        for (int r = 0; r < 4; ++r) rmin[ps][r] = 3.0e38f;

    const char* gH = (const char*)(fTh + (size_t)n*L_*CP);
    const char* gL = (const char*)(fTl + (size_t)n*L_*CP);

    for (int ch = 0; ch < 4; ++ch) {
        __syncthreads();
        // stage 16KB per buffer: LDS[l*128 + (b ^ ((l&7)<<4))] = global[l*128 + b]
        #pragma unroll
        for (int s4 = 0; s4 < 4; ++s4) {
            int d  = (s4*256 + tid) * 16;
            int lr = d >> 7;
            int bo = d & 127;
            int ph = (lr << 7) + (bo ^ ((lr & 7) << 4));
            uint4 vh = *(const uint4*)(gH + (size_t)ch*16384 + d);
            uint4 vl = *(const uint4*)(gL + (size_t)ch*16384 + d);
            *(uint4*)((char*)fBh + ph) = vh;
            *(uint4*)((char*)fBl + ph) = vl;
        }
        if (tid < 128) x2S[tid] = x2buf[n*L_ + ch*128 + tid];
        __syncthreads();

        #pragma unroll
        for (int ls = 0; ls < 2; ++ls) {
            const int lsub = wv*2 + ls;
            const int lrow = lsub*16 + (lane & 15);
            const int g    = lane >> 4;
            bf16x8 bh[2], bl[2];
            #pragma unroll
            for (int ks = 0; ks < 2; ++ks) {
                int bo = (ks*64 + g*16) ^ ((lrow & 7) << 4);
                bh[ks] = *(const bf16x8*)((const char*)fBh + lrow*128 + bo);
                bl[ks] = *(const bf16x8*)((const char*)fBl + lrow*128 + bo);
            }
            float xv = x2S[lsub*16 + (lane & 15)];
            #pragma unroll
            for (int ps = 0; ps < 4; ++ps) {
                f32x4 c = {0.f, 0.f, 0.f, 0.f};
                c = __builtin_amdgcn_mfma_f32_16x16x32_bf16(ah[ps][0], bh[0], c, 0, 0, 0);
                c = __builtin_amdgcn_mfma_f32_16x16x32_bf16(ah[ps][1], bh[1], c, 0, 0, 0);
                c = __builtin_amdgcn_mfma_f32_16x16x32_bf16(al[ps][0], bh[0], c, 0, 0, 0);
                c = __builtin_amdgcn_mfma_f32_16x16x32_bf16(al[ps][1], bh[1], c, 0, 0, 0);
                c = __builtin_amdgcn_mfma_f32_16x16x32_bf16(ah[ps][0], bl[0], c, 0, 0, 0);
                c = __builtin_amdgcn_mfma_f32_16x16x32_bf16(ah[ps][1], bl[1], c, 0, 0, 0);
                #pragma unroll
                for (int r = 0; r < 4; ++r)
                    rmin[ps][r] = fminf(rmin[ps][r], fmaf(-2.f, c[r], xv));
            }
        }
    }

    // min over the 16 l-columns within each 16-lane group
    #pragma unroll
    for (int ps = 0; ps < 4; ++ps)
        #pragma unroll
        for (int r = 0; r < 4; ++r) {
            float v = rmin[ps][r];
            v = fminf(v, __shfl_xor(v, 1));
            v = fminf(v, __shfl_xor(v, 2));
            v = fminf(v, __shfl_xor(v, 4));
            v = fminf(v, __shfl_xor(v, 8));
            rmin[ps][r] = v;
        }
    if ((lane & 15) == 0) {
        const int g = lane >> 4;
        #pragma unroll
        for (int ps = 0; ps < 4; ++ps)
            #pragma unroll
            for (int r = 0; r < 4; ++r)
                redS[wv][ps*16 + g*4 + r] = rmin[ps][r];
    }
    __syncthreads();
    if (tid < 64) {
        float mv = fminf(fminf(redS[0][tid], redS[1][tid]), fminf(redS[2][tid], redS[3][tid]));
        int gp = p0 + tid;
        if (gp < P_) {
            const float4* pr = (const float4*)(proto + (size_t)gp*64);
            float p2 = 0.f;
            #pragma unroll
            for (int q = 0; q < 16; ++q) {
                float4 v = pr[q];
                p2 += v.x*v.x + v.y*v.y + v.z*v.z + v.w*v.w;
            }
            float m = fmaxf(mv + p2, 0.0f);
            md_out[n*P_ + gp] = m;
            acts[n*P_ + gp]   = logf((m + 1.0f) / (m + EPS));
        }
    }
}

// ---------------- Kernel 3: logits = acts @ last_w^T, one wave per output ----------------
__global__ __launch_bounds__(256) void k3_logits(const float* __restrict__ acts,
    const float* __restrict__ last_w, float* __restrict__ out)
{
    const int wid  = (blockIdx.x * 256 + threadIdx.x) >> 6;  // 0..6399
    const int lane = threadIdx.x & 63;
    const int n    = wid / NCLS;
    const int cls  = wid - n * NCLS;

    const float4* a = (const float4*)(acts + (size_t)n*P_);
    const float4* w = (const float4*)(last_w + (size_t)cls*P_);

    float acc = 0.f;
    #pragma unroll
    for (int it = 0; it < 8; ++it) {
        int idx = it*64 + lane;          // float4 index, 0..511
        if (idx < P_/4) {
            float4 av = a[idx]; float4 wv = w[idx];
            acc += av.x*wv.x + av.y*wv.y + av.z*wv.z + av.w*wv.w;
        }
    }
    #pragma unroll
    for (int off = 32; off > 0; off >>= 1)
        acc += __shfl_down(acc, off);
    if (lane == 0)
        out[n*NCLS + cls] = acc;
}

extern "C" void kernel_launch(void* const* d_in, const int* in_sizes, int n_in,
                              void* d_out, int out_size, void* d_ws, size_t ws_size,
                              hipStream_t stream)
{
    const float* x      = (const float*)d_in[0];
    const float* W1     = (const float*)d_in[1];
    const float* b1     = (const float*)d_in[2];
    const float* W2     = (const float*)d_in[3];
    const float* b2     = (const float*)d_in[4];
    const float* proto  = (const float*)d_in[5];
    const float* last_w = (const float*)d_in[6];

    float* out = (float*)d_out;   // [32*200] logits, then [32*2000] min_dist

    // ws layout: fTh 2MB | fTl 2MB | x2buf 64KB | acts 256KB
    unsigned short* fTh = (unsigned short*)d_ws;
    unsigned short* fTl = fTh + (size_t)N_*L_*CP;
    float* x2buf = (float*)(fTl + (size_t)N_*L_*CP);
    float* acts  = x2buf + (size_t)N_*L_;

    k1_conv  <<<dim3(16, 32), 256, 0, stream>>>(x, W1, b1, W2, b2, fTh, fTl, x2buf);
    k2_dist  <<<dim3(32, 32), 256, 0, stream>>>(fTh, fTl, x2buf, proto, out + N_*NCLS, acts);
    k3_logits<<<1600,         256, 0, stream>>>(acts, last_w, out);
}

// Round 8
// 55.793 us; speedup vs baseline: 1.0942x; 1.0816x over previous
//
#include <hip/hip_runtime.h>
#include <math.h>

#define EPS 1e-4f
#define N_   32
#define CIN  128
#define L_   512
#define CP   64
#define P_   2000
#define NCLS 200

typedef __attribute__((ext_vector_type(8))) short bf16x8;
typedef __attribute__((ext_vector_type(4))) float f32x4;

__device__ inline unsigned short f2bf_rne(float f) {
    unsigned int u = __float_as_uint(f);
    unsigned int r = u + 0x7FFFu + ((u >> 16) & 1u);
    return (unsigned short)(r >> 16);
}
__device__ inline float bf2f(unsigned short h) {
    return __uint_as_float(((unsigned int)h) << 16);
}

__device__ inline void gl_lds16(const void* g, void* l) {
    __builtin_amdgcn_global_load_lds(
        (const __attribute__((address_space(1))) unsigned int*)g,
        (__attribute__((address_space(3))) unsigned int*)l, 16, 0, 0);
}

// ---------------- Kernel 1 (R5 version — measured ~4-5us): conv-relu-conv-sigmoid ----------
// 512 blocks (2/CU): block = (n, 32 l). thread = (og: 8-ch group, l).
__global__ __launch_bounds__(256) void k1_conv(const float* __restrict__ x,
    const float* __restrict__ W1, const float* __restrict__ b1,
    const float* __restrict__ W2, const float* __restrict__ b2,
    unsigned short* __restrict__ fTh, unsigned short* __restrict__ fTl,
    float* __restrict__ x2buf)
{
    __shared__ float  xS[128*32];              // 16KB [c][l]
    __shared__ float4 W1s[64][32];             // 32KB [o][c4]
    __shared__ float4 W2s[64][16];             // 16KB [o][c4]
    __shared__ __align__(16) char scratch[8448];  // hS [64][33] f32  OR  fP [2][32][8] uint4
    __shared__ float  x2p[8][32];
    __shared__ float  b1s[64], b2s[64];

    float (*hS)[33]       = (float (*)[33])scratch;
    uint4 (*fP)[32][8]    = (uint4 (*)[32][8])scratch;

    const int tid = threadIdx.x;
    const int wv  = tid >> 6;
    const int n   = blockIdx.y;
    const int lg  = blockIdx.x;

    // ---- async stage x tile [128 c][32 l] into LDS ----
    {
        const float* xbase = x + (size_t)n*CIN*L_ + lg*32;
        const int lane = tid & 63;
        #pragma unroll
        for (int i = 0; i < 4; ++i) {
            int blk = wv*4 + i;                 // 1KB chunk = 8 c-rows
            const float* src = xbase + (size_t)(blk*8 + (lane >> 3))*L_ + (lane & 7)*4;
            gl_lds16(src, &xS[blk*256]);
        }
    }

    const float4* W1g = (const float4*)W1;
    #pragma unroll
    for (int i = 0; i < 8; ++i) {
        int idx = tid + i*256;
        W1s[idx >> 5][idx & 31] = W1g[idx];
    }
    const float4* W2g = (const float4*)W2;
    #pragma unroll
    for (int i = 0; i < 4; ++i) {
        int idx = tid + i*256;
        W2s[idx >> 4][idx & 15] = W2g[idx];
    }
    if (tid < 64) { b1s[tid] = b1[tid]; b2s[tid] = b2[tid]; }
    __syncthreads();

    const int l  = tid & 31;
    const int og = tid >> 5;        // 0..7, 8 output channels each

    float h[8];
    #pragma unroll
    for (int o = 0; o < 8; ++o) h[o] = b1s[og*8 + o];

    #pragma unroll 8
    for (int c4 = 0; c4 < 32; ++c4) {
        float xv0 = xS[(c4*4+0)*32 + l];
        float xv1 = xS[(c4*4+1)*32 + l];
        float xv2 = xS[(c4*4+2)*32 + l];
        float xv3 = xS[(c4*4+3)*32 + l];
        #pragma unroll
        for (int o = 0; o < 8; ++o) {
            float4 w = W1s[og*8+o][c4];
            h[o] = fmaf(w.x, xv0, fmaf(w.y, xv1, fmaf(w.z, xv2, fmaf(w.w, xv3, h[o]))));
        }
    }
    __syncthreads();   // xS done; scratch free to use as hS
    #pragma unroll
    for (int o = 0; o < 8; ++o)
        hS[og*8+o][l] = fmaxf(h[o], 0.0f);
    __syncthreads();

    float f[8];
    #pragma unroll
    for (int o = 0; o < 8; ++o) f[o] = b2s[og*8 + o];
    #pragma unroll 4
    for (int c4 = 0; c4 < 16; ++c4) {
        float h0 = hS[c4*4+0][l];
        float h1 = hS[c4*4+1][l];
        float h2 = hS[c4*4+2][l];
        float h3 = hS[c4*4+3][l];
        #pragma unroll
        for (int o = 0; o < 8; ++o) {
            float4 w = W2s[og*8+o][c4];
            f[o] = fmaf(w.x, h0, fmaf(w.y, h1, fmaf(w.z, h2, fmaf(w.w, h3, f[o]))));
        }
    }

    unsigned int packH[4], packL[4];
    float s = 0.0f;
    #pragma unroll
    for (int o = 0; o < 8; ++o) {
        float v = 1.0f / (1.0f + expf(-f[o]));
        unsigned short hb = f2bf_rne(v);
        unsigned short lb = f2bf_rne(v - bf2f(hb));
        if (o & 1) { packH[o>>1] |= ((unsigned)hb) << 16; packL[o>>1] |= ((unsigned)lb) << 16; }
        else       { packH[o>>1] = hb;                     packL[o>>1] = lb; }
        s = fmaf(v, v, s);
    }
    x2p[og][l] = s;
    __syncthreads();   // hS reads done; scratch reused as fP bounce

    fP[0][l][og ^ (l & 7)] = make_uint4(packH[0],packH[1],packH[2],packH[3]);
    fP[1][l][og ^ (l & 7)] = make_uint4(packL[0],packL[1],packL[2],packL[3]);
    __syncthreads();

    // coalesced stores: [n][l][c] bf16, 64 c per l = 8 uint4
    uint4* gH4 = (uint4*)fTh + ((size_t)(n*L_ + lg*32))*8;
    uint4* gL4 = (uint4*)fTl + ((size_t)(n*L_ + lg*32))*8;
    {
        int ll = tid >> 3, u = tid & 7;
        gH4[tid] = fP[0][ll][u ^ (ll & 7)];
        gL4[tid] = fP[1][ll][u ^ (ll & 7)];
    }
    if (tid < 32) {
        float v = 0.f;
        #pragma unroll
        for (int g = 0; g < 8; ++g) v += x2p[g][tid];
        x2buf[n*L_ + lg*32 + tid] = v;
    }
}

// ---------------- Kernel 2: split-bf16 MFMA distance scan + min + activation ----------------
// 32-proto tile per block: A-frags only 32 VGPR -> no spill, no launch-bounds cap.
// grid (63, 32) = 2016 blocks.
__global__ __launch_bounds__(256) void k2_dist(
    const unsigned short* __restrict__ fTh, const unsigned short* __restrict__ fTl,
    const float* __restrict__ x2buf, const float* __restrict__ proto,
    float* __restrict__ md_out, float* __restrict__ acts)
{
    __shared__ unsigned short fBh[8192];  // [128 l][64 k] bf16, XOR-swizzled rows (16KB)
    __shared__ unsigned short fBl[8192];
    __shared__ float x2S[128];
    __shared__ float redS[4][32];

    const int tid  = threadIdx.x;
    const int lane = tid & 63;
    const int wv   = tid >> 6;
    const int n    = blockIdx.y;
    const int p0   = blockIdx.x * 32;

    // ---- A fragments: proto f32 -> split bf16, kept in registers (32 VGPRs) ----
    bf16x8 ah[2][2], al[2][2];
    {
        const int pr = lane & 15;
        const int g  = lane >> 4;
        #pragma unroll
        for (int ps = 0; ps < 2; ++ps) {
            int p = p0 + ps*16 + pr;
            #pragma unroll
            for (int ks = 0; ks < 2; ++ks) {
                float v[8];
                if (p < P_) {
                    const float4* src = (const float4*)(proto + (size_t)p*64 + ks*32 + g*8);
                    float4 a0 = src[0], a1 = src[1];
                    v[0]=a0.x; v[1]=a0.y; v[2]=a0.z; v[3]=a0.w;
                    v[4]=a1.x; v[5]=a1.y; v[6]=a1.z; v[7]=a1.w;
                } else {
                    #pragma unroll
                    for (int j = 0; j < 8; ++j) v[j] = 0.f;
                }
                bf16x8 H, Lo;
                #pragma unroll
                for (int j = 0; j < 8; ++j) {
                    unsigned short hb = f2bf_rne(v[j]);
                    unsigned short lb = f2bf_rne(v[j] - bf2f(hb));
                    H[j] = (short)hb; Lo[j] = (short)lb;
                }
                ah[ps][ks] = H; al[ps][ks] = Lo;
            }
        }
    }

    float rmin[2][4];
    #pragma unroll
    for (int ps = 0; ps < 2; ++ps)
        #pragma unroll
        for (int r = 0; r < 4; ++r) rmin[ps][r] = 3.0e38f;

    const char* gH = (const char*)(fTh + (size_t)n*L_*CP);
    const char* gL = (const char*)(fTl + (size_t)n*L_*CP);

    for (int ch = 0; ch < 4; ++ch) {
        __syncthreads();
        // stage 16KB per buffer: LDS[l*128 + (b ^ ((l&7)<<4))] = global[l*128 + b]
        #pragma unroll
        for (int s4 = 0; s4 < 4; ++s4) {
            int d  = (s4*256 + tid) * 16;
            int lr = d >> 7;
            int bo = d & 127;
            int ph = (lr << 7) + (bo ^ ((lr & 7) << 4));
            uint4 vh = *(const uint4*)(gH + (size_t)ch*16384 + d);
            uint4 vl = *(const uint4*)(gL + (size_t)ch*16384 + d);
            *(uint4*)((char*)fBh + ph) = vh;
            *(uint4*)((char*)fBl + ph) = vl;
        }
        if (tid < 128) x2S[tid] = x2buf[n*L_ + ch*128 + tid];
        __syncthreads();

        #pragma unroll
        for (int ls = 0; ls < 2; ++ls) {
            const int lsub = wv*2 + ls;
            const int lrow = lsub*16 + (lane & 15);
            const int g    = lane >> 4;
            bf16x8 bh[2], bl[2];
            #pragma unroll
            for (int ks = 0; ks < 2; ++ks) {
                int bo = (ks*64 + g*16) ^ ((lrow & 7) << 4);
                bh[ks] = *(const bf16x8*)((const char*)fBh + lrow*128 + bo);
                bl[ks] = *(const bf16x8*)((const char*)fBl + lrow*128 + bo);
            }
            float xv = x2S[lsub*16 + (lane & 15)];
            #pragma unroll
            for (int ps = 0; ps < 2; ++ps) {
                f32x4 c = {0.f, 0.f, 0.f, 0.f};
                c = __builtin_amdgcn_mfma_f32_16x16x32_bf16(ah[ps][0], bh[0], c, 0, 0, 0);
                c = __builtin_amdgcn_mfma_f32_16x16x32_bf16(ah[ps][1], bh[1], c, 0, 0, 0);
                c = __builtin_amdgcn_mfma_f32_16x16x32_bf16(al[ps][0], bh[0], c, 0, 0, 0);
                c = __builtin_amdgcn_mfma_f32_16x16x32_bf16(al[ps][1], bh[1], c, 0, 0, 0);
                c = __builtin_amdgcn_mfma_f32_16x16x32_bf16(ah[ps][0], bl[0], c, 0, 0, 0);
                c = __builtin_amdgcn_mfma_f32_16x16x32_bf16(ah[ps][1], bl[1], c, 0, 0, 0);
                #pragma unroll
                for (int r = 0; r < 4; ++r)
                    rmin[ps][r] = fminf(rmin[ps][r], fmaf(-2.f, c[r], xv));
            }
        }
    }

    // min over the 16 l-columns within each 16-lane group
    #pragma unroll
    for (int ps = 0; ps < 2; ++ps)
        #pragma unroll
        for (int r = 0; r < 4; ++r) {
            float v = rmin[ps][r];
            v = fminf(v, __shfl_xor(v, 1));
            v = fminf(v, __shfl_xor(v, 2));
            v = fminf(v, __shfl_xor(v, 4));
            v = fminf(v, __shfl_xor(v, 8));
            rmin[ps][r] = v;
        }
    if ((lane & 15) == 0) {
        const int g = lane >> 4;
        #pragma unroll
        for (int ps = 0; ps < 2; ++ps)
            #pragma unroll
            for (int r = 0; r < 4; ++r)
                redS[wv][ps*16 + g*4 + r] = rmin[ps][r];
    }
    __syncthreads();
    if (tid < 32) {
        float mv = fminf(fminf(redS[0][tid], redS[1][tid]), fminf(redS[2][tid], redS[3][tid]));
        int gp = p0 + tid;
        if (gp < P_) {
            const float4* pr = (const float4*)(proto + (size_t)gp*64);
            float p2 = 0.f;
            #pragma unroll
            for (int q = 0; q < 16; ++q) {
                float4 v = pr[q];
                p2 += v.x*v.x + v.y*v.y + v.z*v.z + v.w*v.w;
            }
            float m = fmaxf(mv + p2, 0.0f);
            md_out[n*P_ + gp] = m;
            acts[n*P_ + gp]   = logf((m + 1.0f) / (m + EPS));
        }
    }
}

// ---------------- Kernel 3: logits = acts @ last_w^T, one wave per output ----------------
__global__ __launch_bounds__(256) void k3_logits(const float* __restrict__ acts,
    const float* __restrict__ last_w, float* __restrict__ out)
{
    const int wid  = (blockIdx.x * 256 + threadIdx.x) >> 6;  // 0..6399
    const int lane = threadIdx.x & 63;
    const int n    = wid / NCLS;
    const int cls  = wid - n * NCLS;

    const float4* a = (const float4*)(acts + (size_t)n*P_);
    const float4* w = (const float4*)(last_w + (size_t)cls*P_);

    float acc = 0.f;
    #pragma unroll
    for (int it = 0; it < 8; ++it) {
        int idx = it*64 + lane;          // float4 index, 0..511
        if (idx < P_/4) {
            float4 av = a[idx]; float4 wv = w[idx];
            acc += av.x*wv.x + av.y*wv.y + av.z*wv.z + av.w*wv.w;
        }
    }
    #pragma unroll
    for (int off = 32; off > 0; off >>= 1)
        acc += __shfl_down(acc, off);
    if (lane == 0)
        out[n*NCLS + cls] = acc;
}

extern "C" void kernel_launch(void* const* d_in, const int* in_sizes, int n_in,
                              void* d_out, int out_size, void* d_ws, size_t ws_size,
                              hipStream_t stream)
{
    const float* x      = (const float*)d_in[0];
    const float* W1     = (const float*)d_in[1];
    const float* b1     = (const float*)d_in[2];
    const float* W2     = (const float*)d_in[3];
    const float* b2     = (const float*)d_in[4];
    const float* proto  = (const float*)d_in[5];
    const float* last_w = (const float*)d_in[6];

    float* out = (float*)d_out;   // [32*200] logits, then [32*2000] min_dist

    // ws layout: fTh 2MB | fTl 2MB | x2buf 64KB | acts 256KB
    unsigned short* fTh = (unsigned short*)d_ws;
    unsigned short* fTl = fTh + (size_t)N_*L_*CP;
    float* x2buf = (float*)(fTl + (size_t)N_*L_*CP);
    float* acts  = x2buf + (size_t)N_*L_;

    k1_conv  <<<dim3(16, 32), 256, 0, stream>>>(x, W1, b1, W2, b2, fTh, fTl, x2buf);
    k2_dist  <<<dim3(63, 32), 256, 0, stream>>>(fTh, fTl, x2buf, proto, out + N_*NCLS, acts);
    k3_logits<<<1600,         256, 0, stream>>>(acts, last_w, out);
}

// Round 9
// 51.105 us; speedup vs baseline: 1.1946x; 1.0917x over previous
//
#include <hip/hip_runtime.h>
#include <math.h>

#define EPS 1e-4f
#define N_   32
#define CIN  128
#define L_   512
#define CP   64
#define P_   2000
#define NCLS 200

typedef __attribute__((ext_vector_type(8))) short bf16x8;
typedef __attribute__((ext_vector_type(4))) float f32x4;

__device__ inline unsigned short f2bf_rne(float f) {
    unsigned int u = __float_as_uint(f);
    unsigned int r = u + 0x7FFFu + ((u >> 16) & 1u);
    return (unsigned short)(r >> 16);
}
__device__ inline float bf2f(unsigned short h) {
    return __uint_as_float(((unsigned int)h) << 16);
}

__device__ inline void gl_lds16(const void* g, void* l) {
    __builtin_amdgcn_global_load_lds(
        (const __attribute__((address_space(1))) unsigned int*)g,
        (__attribute__((address_space(3))) unsigned int*)l, 16, 0, 0);
}

// ---------------- Kernel 0: proto f32 -> split bf16 (hi/lo) + p2 ----------------
// grid 500 x 256: thread = (p_local = tid>>6, k = tid&63)
__global__ __launch_bounds__(256) void k0_proto(const float* __restrict__ proto,
    unsigned short* __restrict__ ph, unsigned short* __restrict__ pl,
    float* __restrict__ p2)
{
    const int tid = threadIdx.x;
    const int p   = blockIdx.x*4 + (tid >> 6);
    const int k   = tid & 63;
    float v = proto[(size_t)p*64 + k];
    unsigned short hb = f2bf_rne(v);
    unsigned short lb = f2bf_rne(v - bf2f(hb));
    ph[(size_t)p*64 + k] = hb;
    pl[(size_t)p*64 + k] = lb;
    float s = v*v;
    #pragma unroll
    for (int off = 32; off > 0; off >>= 1) s += __shfl_xor(s, off);
    if (k == 0) p2[p] = s;
}

// ---------------- Kernel 1 (R5 version, measured ~4-5us): conv-relu-conv-sigmoid ------------
__global__ __launch_bounds__(256) void k1_conv(const float* __restrict__ x,
    const float* __restrict__ W1, const float* __restrict__ b1,
    const float* __restrict__ W2, const float* __restrict__ b2,
    unsigned short* __restrict__ fTh, unsigned short* __restrict__ fTl,
    float* __restrict__ x2buf)
{
    __shared__ float  xS[128*32];              // 16KB [c][l]
    __shared__ float4 W1s[64][32];             // 32KB [o][c4]
    __shared__ float4 W2s[64][16];             // 16KB [o][c4]
    __shared__ __align__(16) char scratch[8448];  // hS [64][33] f32  OR  fP [2][32][8] uint4
    __shared__ float  x2p[8][32];
    __shared__ float  b1s[64], b2s[64];

    float (*hS)[33]       = (float (*)[33])scratch;
    uint4 (*fP)[32][8]    = (uint4 (*)[32][8])scratch;

    const int tid = threadIdx.x;
    const int wv  = tid >> 6;
    const int n   = blockIdx.y;
    const int lg  = blockIdx.x;

    {
        const float* xbase = x + (size_t)n*CIN*L_ + lg*32;
        const int lane = tid & 63;
        #pragma unroll
        for (int i = 0; i < 4; ++i) {
            int blk = wv*4 + i;
            const float* src = xbase + (size_t)(blk*8 + (lane >> 3))*L_ + (lane & 7)*4;
            gl_lds16(src, &xS[blk*256]);
        }
    }

    const float4* W1g = (const float4*)W1;
    #pragma unroll
    for (int i = 0; i < 8; ++i) {
        int idx = tid + i*256;
        W1s[idx >> 5][idx & 31] = W1g[idx];
    }
    const float4* W2g = (const float4*)W2;
    #pragma unroll
    for (int i = 0; i < 4; ++i) {
        int idx = tid + i*256;
        W2s[idx >> 4][idx & 15] = W2g[idx];
    }
    if (tid < 64) { b1s[tid] = b1[tid]; b2s[tid] = b2[tid]; }
    __syncthreads();

    const int l  = tid & 31;
    const int og = tid >> 5;

    float h[8];
    #pragma unroll
    for (int o = 0; o < 8; ++o) h[o] = b1s[og*8 + o];

    #pragma unroll 8
    for (int c4 = 0; c4 < 32; ++c4) {
        float xv0 = xS[(c4*4+0)*32 + l];
        float xv1 = xS[(c4*4+1)*32 + l];
        float xv2 = xS[(c4*4+2)*32 + l];
        float xv3 = xS[(c4*4+3)*32 + l];
        #pragma unroll
        for (int o = 0; o < 8; ++o) {
            float4 w = W1s[og*8+o][c4];
            h[o] = fmaf(w.x, xv0, fmaf(w.y, xv1, fmaf(w.z, xv2, fmaf(w.w, xv3, h[o]))));
        }
    }
    __syncthreads();
    #pragma unroll
    for (int o = 0; o < 8; ++o)
        hS[og*8+o][l] = fmaxf(h[o], 0.0f);
    __syncthreads();

    float f[8];
    #pragma unroll
    for (int o = 0; o < 8; ++o) f[o] = b2s[og*8 + o];
    #pragma unroll 4
    for (int c4 = 0; c4 < 16; ++c4) {
        float h0 = hS[c4*4+0][l];
        float h1 = hS[c4*4+1][l];
        float h2 = hS[c4*4+2][l];
        float h3 = hS[c4*4+3][l];
        #pragma unroll
        for (int o = 0; o < 8; ++o) {
            float4 w = W2s[og*8+o][c4];
            f[o] = fmaf(w.x, h0, fmaf(w.y, h1, fmaf(w.z, h2, fmaf(w.w, h3, f[o]))));
        }
    }

    unsigned int packH[4], packL[4];
    float s = 0.0f;
    #pragma unroll
    for (int o = 0; o < 8; ++o) {
        float v = 1.0f / (1.0f + expf(-f[o]));
        unsigned short hb = f2bf_rne(v);
        unsigned short lb = f2bf_rne(v - bf2f(hb));
        if (o & 1) { packH[o>>1] |= ((unsigned)hb) << 16; packL[o>>1] |= ((unsigned)lb) << 16; }
        else       { packH[o>>1] = hb;                     packL[o>>1] = lb; }
        s = fmaf(v, v, s);
    }
    x2p[og][l] = s;
    __syncthreads();

    fP[0][l][og ^ (l & 7)] = make_uint4(packH[0],packH[1],packH[2],packH[3]);
    fP[1][l][og ^ (l & 7)] = make_uint4(packL[0],packL[1],packL[2],packL[3]);
    __syncthreads();

    uint4* gH4 = (uint4*)fTh + ((size_t)(n*L_ + lg*32))*8;
    uint4* gL4 = (uint4*)fTl + ((size_t)(n*L_ + lg*32))*8;
    {
        int ll = tid >> 3, u = tid & 7;
        gH4[tid] = fP[0][ll][u ^ (ll & 7)];
        gL4[tid] = fP[1][ll][u ^ (ll & 7)];
    }
    if (tid < 32) {
        float v = 0.f;
        #pragma unroll
        for (int g = 0; g < 8; ++g) v += x2p[g][tid];
        x2buf[n*L_ + lg*32 + tid] = v;
    }
}

// ---------------- Kernel 2: f staged ONCE per block; protos streamed to registers ----------
// grid (8 lg, 32 n) x 512 thr (8 waves). Wave takes proto-tiles pt = wv, wv+8, ... (125 total).
// Writes partial min over this block's 64 l to md_part[lg][n][p].
__global__ __launch_bounds__(512) void k2_dist(
    const unsigned short* __restrict__ fTh, const unsigned short* __restrict__ fTl,
    const unsigned short* __restrict__ ph, const unsigned short* __restrict__ pl,
    const float* __restrict__ x2buf, float* __restrict__ md_part)
{
    __shared__ unsigned short fBh[4096];  // [64 l][64 k] bf16, XOR-swizzled rows (8KB)
    __shared__ unsigned short fBl[4096];
    __shared__ float x2S[64];

    const int tid  = threadIdx.x;
    const int lane = tid & 63;
    const int wv   = tid >> 6;          // 0..7
    const int n    = blockIdx.y;
    const int lg   = blockIdx.x;        // 0..7, 64 l each

    // ---- stage f chunk (hi+lo), swizzled: one uint4 per thread per array ----
    {
        const char* gH = (const char*)(fTh + ((size_t)n*L_ + lg*64)*CP);
        const char* gL = (const char*)(fTl + ((size_t)n*L_ + lg*64)*CP);
        int d  = tid * 16;              // 0..8191
        int lr = d >> 7;
        int bo = d & 127;
        int pb = (lr << 7) + (bo ^ ((lr & 7) << 4));
        *(uint4*)((char*)fBh + pb) = *(const uint4*)(gH + d);
        *(uint4*)((char*)fBl + pb) = *(const uint4*)(gL + d);
    }
    if (tid < 64) x2S[tid] = x2buf[n*L_ + lg*64 + tid];
    __syncthreads();

    // ---- preload B fragments for the 4 l-tiles into registers (64 VGPR) ----
    const int g = lane >> 4;
    bf16x8 bh[4][2], bl[4][2];
    float  xv[4];
    #pragma unroll
    for (int lt = 0; lt < 4; ++lt) {
        int lrow = lt*16 + (lane & 15);
        #pragma unroll
        for (int ks = 0; ks < 2; ++ks) {
            int bo = (ks*64 + g*16) ^ ((lrow & 7) << 4);
            bh[lt][ks] = *(const bf16x8*)((const char*)fBh + lrow*128 + bo);
            bl[lt][ks] = *(const bf16x8*)((const char*)fBl + lrow*128 + bo);
        }
        xv[lt] = x2S[lt*16 + (lane & 15)];
    }

    float* mp = md_part + ((size_t)lg*N_ + n)*P_;

    // ---- stream proto tiles ----
    for (int pt = wv; pt < P_/16; pt += 8) {
        const int p = pt*16 + (lane & 15);
        bf16x8 a_h[2], a_l[2];
        #pragma unroll
        for (int ks = 0; ks < 2; ++ks) {
            a_h[ks] = *(const bf16x8*)(ph + (size_t)p*64 + ks*32 + g*8);
            a_l[ks] = *(const bf16x8*)(pl + (size_t)p*64 + ks*32 + g*8);
        }
        float cmin[4];
        #pragma unroll
        for (int r = 0; r < 4; ++r) cmin[r] = 3.0e38f;

        #pragma unroll
        for (int lt = 0; lt < 4; ++lt) {
            f32x4 c = {0.f, 0.f, 0.f, 0.f};
            c = __builtin_amdgcn_mfma_f32_16x16x32_bf16(a_h[0], bh[lt][0], c, 0, 0, 0);
            c = __builtin_amdgcn_mfma_f32_16x16x32_bf16(a_h[1], bh[lt][1], c, 0, 0, 0);
            c = __builtin_amdgcn_mfma_f32_16x16x32_bf16(a_l[0], bh[lt][0], c, 0, 0, 0);
            c = __builtin_amdgcn_mfma_f32_16x16x32_bf16(a_l[1], bh[lt][1], c, 0, 0, 0);
            c = __builtin_amdgcn_mfma_f32_16x16x32_bf16(a_h[0], bl[lt][0], c, 0, 0, 0);
            c = __builtin_amdgcn_mfma_f32_16x16x32_bf16(a_h[1], bl[lt][1], c, 0, 0, 0);
            #pragma unroll
            for (int r = 0; r < 4; ++r)
                cmin[r] = fminf(cmin[r], fmaf(-2.f, c[r], xv[lt]));
        }
        // reduce over the 16 l-columns within each 16-lane group
        #pragma unroll
        for (int r = 0; r < 4; ++r) {
            float v = cmin[r];
            v = fminf(v, __shfl_xor(v, 1));
            v = fminf(v, __shfl_xor(v, 2));
            v = fminf(v, __shfl_xor(v, 4));
            v = fminf(v, __shfl_xor(v, 8));
            cmin[r] = v;
        }
        if ((lane & 15) == 0) {
            int prow = pt*16 + g*4;
            #pragma unroll
            for (int r = 0; r < 4; ++r) mp[prow + r] = cmin[r];
        }
    }
}

// ---------------- Kernel 2b: min over 8 l-chunks + p2 + relu + log ----------------
__global__ __launch_bounds__(256) void k2b_reduce(const float* __restrict__ md_part,
    const float* __restrict__ p2, float* __restrict__ md_out, float* __restrict__ acts)
{
    const int p = blockIdx.x*256 + threadIdx.x;
    const int n = blockIdx.y;
    if (p < P_) {
        float mv = 3.0e38f;
        #pragma unroll
        for (int lg = 0; lg < 8; ++lg)
            mv = fminf(mv, md_part[((size_t)lg*N_ + n)*P_ + p]);
        float m = fmaxf(mv + p2[p], 0.0f);
        md_out[n*P_ + p] = m;
        acts[n*P_ + p]   = logf((m + 1.0f) / (m + EPS));
    }
}

// ---------------- Kernel 3: logits = acts @ last_w^T, one wave per output ----------------
__global__ __launch_bounds__(256) void k3_logits(const float* __restrict__ acts,
    const float* __restrict__ last_w, float* __restrict__ out)
{
    const int wid  = (blockIdx.x * 256 + threadIdx.x) >> 6;  // 0..6399
    const int lane = threadIdx.x & 63;
    const int n    = wid / NCLS;
    const int cls  = wid - n * NCLS;

    const float4* a = (const float4*)(acts + (size_t)n*P_);
    const float4* w = (const float4*)(last_w + (size_t)cls*P_);

    float acc = 0.f;
    #pragma unroll
    for (int it = 0; it < 8; ++it) {
        int idx = it*64 + lane;
        if (idx < P_/4) {
            float4 av = a[idx]; float4 wv = w[idx];
            acc += av.x*wv.x + av.y*wv.y + av.z*wv.z + av.w*wv.w;
        }
    }
    #pragma unroll
    for (int off = 32; off > 0; off >>= 1)
        acc += __shfl_down(acc, off);
    if (lane == 0)
        out[n*NCLS + cls] = acc;
}

extern "C" void kernel_launch(void* const* d_in, const int* in_sizes, int n_in,
                              void* d_out, int out_size, void* d_ws, size_t ws_size,
                              hipStream_t stream)
{
    const float* x      = (const float*)d_in[0];
    const float* W1     = (const float*)d_in[1];
    const float* b1     = (const float*)d_in[2];
    const float* W2     = (const float*)d_in[3];
    const float* b2     = (const float*)d_in[4];
    const float* proto  = (const float*)d_in[5];
    const float* last_w = (const float*)d_in[6];

    float* out = (float*)d_out;   // [32*200] logits, then [32*2000] min_dist

    // ws layout (≈6.9MB):
    // fTh 2MB | fTl 2MB | x2buf 64KB | acts 256KB | ph 256KB | pl 256KB | p2 8KB | md_part 2MB
    unsigned short* fTh = (unsigned short*)d_ws;
    unsigned short* fTl = fTh + (size_t)N_*L_*CP;
    float* x2buf = (float*)(fTl + (size_t)N_*L_*CP);
    float* acts  = x2buf + (size_t)N_*L_;
    unsigned short* ph = (unsigned short*)(acts + (size_t)N_*P_);
    unsigned short* pl = ph + (size_t)P_*CP;
    float* p2      = (float*)(pl + (size_t)P_*CP);
    float* md_part = p2 + P_;

    k0_proto  <<<500,          256, 0, stream>>>(proto, ph, pl, p2);
    k1_conv   <<<dim3(16, 32), 256, 0, stream>>>(x, W1, b1, W2, b2, fTh, fTl, x2buf);
    k2_dist   <<<dim3(8, 32),  512, 0, stream>>>(fTh, fTl, ph, pl, x2buf, md_part);
    k2b_reduce<<<dim3(8, 32),  256, 0, stream>>>(md_part, p2, out + N_*NCLS, acts);
    k3_logits <<<1600,         256, 0, stream>>>(acts, last_w, out);
}